// Round 4
// baseline (305.646 us; speedup 1.0000x reference)
//
#include <hip/hip_runtime.h>
#include <hip/hip_bf16.h>

// Problem constants
#define BB 8
#define NN 4096
#define EE 65536            // edges per graph
#define BE (BB*EE)          // 524288 total edges
#define BN (BB*NN)          // 32768 total nodes
#define INF 128
#define HID 512
#define CC 2
#define OUTC 10
#define ELLCAP 64           // max in-degree capacity (Binomial mean 16, P(>=64)<1e-13)

typedef __bf16 bf16x8_t __attribute__((ext_vector_type(8)));
typedef float  f32x4_t  __attribute__((ext_vector_type(4)));

__device__ __forceinline__ ushort f2bf(float f) {
  union { float f; unsigned u; } v; v.f = f;
  unsigned r = v.u + 0x7FFFu + ((v.u >> 16) & 1u);   // RNE
  return (ushort)(r >> 16);
}
__device__ __forceinline__ float bf2f(ushort s) {
  union { unsigned u; float f; } v; v.u = ((unsigned)s) << 16;
  return v.f;
}

// ---------------------------------------------------------------------------
// Kernel FRONT (fused): five independent prep stages in one launch.
//   [0,4096)    : cast_x  (x fp32 -> Ab[:,128:256] bf16), graph = blk&7 (XCD)
//   [4096,6144) : ell_build, graph = (blk-4096)&7
//   [6144,6656) : cast_w  (pre-transposed bf16 weights)
//   [6656,7168) : Wa/Wb precompute: Wa=0.5*Wrel3@Wlin1, Wb=0.5*Wroot3@Wlin1
//                 (tail linear-collapse; weights-only, hidden off critical path)
//   [7168,7176) : bc = brel3@Wlin1 + blin1
// ---------------------------------------------------------------------------
__global__ __launch_bounds__(256) void front(
    const int* __restrict__ src, const int* __restrict__ dst,
    const float* __restrict__ ew, const float* __restrict__ x,
    const float* __restrict__ Wrel, const float* __restrict__ Wroot,
    const float* __restrict__ Wrel3, const float* __restrict__ Wroot3,
    const float* __restrict__ brel3,
    const float* __restrict__ Wlin1, const float* __restrict__ blin1,
    int* __restrict__ deg, int2* __restrict__ ell,
    ushort* __restrict__ Ab, ushort* __restrict__ Bb,
    float* __restrict__ Wa, float* __restrict__ Wb, float* __restrict__ bc) {
  int blk = blockIdx.x;
  int tid = threadIdx.x;
  if (blk < 4096) {
    // graph = blk&7, 512 blocks per graph, 8 rows (256 float4) per block
    int g = (blk & 7) * 131072 + (blk >> 3) * 256 + tid;   // 0..1048575
    float4 v = *(const float4*)&x[(size_t)g * 4];
    int m = g >> 5;
    int kin = (g & 31) * 4;
    ushort4 o;
    o.x = f2bf(v.x); o.y = f2bf(v.y); o.z = f2bf(v.z); o.w = f2bf(v.w);
    *(ushort4*)&Ab[(size_t)m * 256 + 128 + kin] = o;
  } else if (blk < 6144) {
    int bl = blk - 4096;                       // 0..2047 (2048 ≡ 0 mod 8)
    int e = (bl & 7) * EE + (bl >> 3) * 256 + tid;   // 0..524287
    int d = dst[e];
    int p = atomicAdd(&deg[d], 1);
    if (p < ELLCAP) {
      int2 v; v.x = src[e]; v.y = __float_as_int(ew[e]);
      ell[(size_t)d * ELLCAP + p] = v;
    }
  } else if (blk < 6656) {
    int g = (blk - 6144) * 256 + tid;          // 0..131071
    int n = g & 511, k = g >> 9;
    float w = (k < 128) ? Wrel[k * 512 + n] : Wroot[(k - 128) * 512 + n];
    Bb[n * 256 + k] = f2bf(w);
  } else if (blk < 7168) {
    // Wa/Wb tile: p in [0,512): wsel=p&1; q=p>>1: fc=q&7 (64-f), kc=q>>3 (16-k)
    int p = blk - 6656;
    int wsel = p & 1;
    int q = p >> 1;
    int fc = q & 7, kc = q >> 3;
    const float* Wsrc = wsel ? Wroot3 : Wrel3;
    float* Wdst = wsel ? Wb : Wa;
    int f = fc * 64 + (tid & 63);
    int k0 = kc * 16 + (tid >> 6) * 4;
    float acc0 = 0.f, acc1 = 0.f, acc2 = 0.f, acc3 = 0.f;
    for (int j = 0; j < 512; ++j) {
      float wl = Wlin1[j * 512 + f];
      acc0 += Wsrc[(k0 + 0) * 512 + j] * wl;
      acc1 += Wsrc[(k0 + 1) * 512 + j] * wl;
      acc2 += Wsrc[(k0 + 2) * 512 + j] * wl;
      acc3 += Wsrc[(k0 + 3) * 512 + j] * wl;
    }
    Wdst[(k0 + 0) * 512 + f] = 0.5f * acc0;
    Wdst[(k0 + 1) * 512 + f] = 0.5f * acc1;
    Wdst[(k0 + 2) * 512 + f] = 0.5f * acc2;
    Wdst[(k0 + 3) * 512 + f] = 0.5f * acc3;
  } else {
    // bc[f] = brel3 @ Wlin1[:,f] + blin1[f]; 8 blocks x 64 f
    __shared__ float red[4][64];
    int bcb = blk - 7168;
    int f = bcb * 64 + (tid & 63);
    int ks = tid >> 6;
    float acc = 0.f;
    for (int j = ks * 128; j < ks * 128 + 128; ++j)
      acc += brel3[j] * Wlin1[j * 512 + f];
    red[ks][tid & 63] = acc;
    __syncthreads();
    if (ks == 0) {
      float v = red[0][tid] + red[1][tid] + red[2][tid] + red[3][tid];
      bc[f] = v + blin1[f];
    }
  }
}

// ---------------------------------------------------------------------------
// Kernel A5: gather  A[n, 0:128] = bf16( sum_j w_j * xbf16[src_j,:] )
// One node per WAVE; 4 edges per iteration: lane l -> edge slot (l>>4),
// feature slice (l&15)*8 as uint4 (8 bf16, 16B). XCD-locality: blk&7 = graph.
// ---------------------------------------------------------------------------
__global__ __launch_bounds__(256) void gather_ell(
    const int* __restrict__ deg, const int2* __restrict__ ell,
    ushort* __restrict__ Ab) {
  int blk = blockIdx.x;
  int n = (blk & 7) * NN + (blk >> 3) * 4 + (threadIdx.x >> 6);
  int lane = threadIdx.x & 63;
  int l4 = lane >> 4;          // edge slot 0..3
  int fl = lane & 15;          // feature slice
  int d = deg[n]; if (d > ELLCAP) d = ELLCAP;
  const int2* ep = ell + (size_t)n * ELLCAP;

  float a[8] = {0, 0, 0, 0, 0, 0, 0, 0};
  int j = 0;
  for (; j + 7 < d; j += 8) {
    int2 v0 = ep[j + l4];
    int2 v1 = ep[j + 4 + l4];
    uint4 u0 = *(const uint4*)&Ab[(size_t)v0.x * 256 + 128 + fl * 8];
    uint4 u1 = *(const uint4*)&Ab[(size_t)v1.x * 256 + 128 + fl * 8];
    float w0 = __int_as_float(v0.y);
    float w1 = __int_as_float(v1.y);
    const ushort* s0 = (const ushort*)&u0;
    const ushort* s1 = (const ushort*)&u1;
#pragma unroll
    for (int q = 0; q < 8; ++q)
      a[q] += w0 * bf2f(s0[q]) + w1 * bf2f(s1[q]);
  }
  for (; j + 3 < d; j += 4) {
    int2 v0 = ep[j + l4];
    uint4 u0 = *(const uint4*)&Ab[(size_t)v0.x * 256 + 128 + fl * 8];
    float w0 = __int_as_float(v0.y);
    const ushort* s0 = (const ushort*)&u0;
#pragma unroll
    for (int q = 0; q < 8; ++q)
      a[q] += w0 * bf2f(s0[q]);
  }
  {
    int idx = j + l4;
    if (idx < d) {
      int2 v0 = ep[idx];
      uint4 u0 = *(const uint4*)&Ab[(size_t)v0.x * 256 + 128 + fl * 8];
      float w0 = __int_as_float(v0.y);
      const ushort* s0 = (const ushort*)&u0;
#pragma unroll
      for (int q = 0; q < 8; ++q)
        a[q] += w0 * bf2f(s0[q]);
    }
  }
  // fold the 4 edge slots (lanes l, l^16, l^32, l^48)
#pragma unroll
  for (int q = 0; q < 8; ++q) {
    a[q] += __shfl_xor(a[q], 16, 64);
    a[q] += __shfl_xor(a[q], 32, 64);
  }
  if (l4 == 0) {
    ushort o[8];
#pragma unroll
    for (int q = 0; q < 8; ++q) o[q] = f2bf(a[q]);
    *(uint4*)&Ab[(size_t)n * 256 + fl * 8] = *(const uint4*)o;
  }
}

// ---------------------------------------------------------------------------
// Kernel C: single-stage MFMA GEMM. 64x64 tile, FULL K=256 staged once,
// XOR-swizzled, ONE barrier before MFMA. Coalesced C epilogue via CPAD=72.
// XCD mapping graph-aligned: xcd=blk&7 -> rows [xcd*4096, ...).
// ---------------------------------------------------------------------------
#define CPAD 72
__global__ __launch_bounds__(256) void gemm_mfma(
    const ushort* __restrict__ Ab, const ushort* __restrict__ Bb,
    const float* __restrict__ brel, ushort* __restrict__ hw) {
  __shared__ ushort As[64 * 256];   // 32 KB
  __shared__ ushort Bs[64 * 256];   // 32 KB
  int tid = threadIdx.x;
  int blk = blockIdx.x;
  int xcd = blk & 7;
  int idx = blk >> 3;                  // 0..511
  int by = xcd * 64 + (idx & 63);      // 0..511
  int bx = idx >> 6;                   // 0..7
  int m0 = by * 64, n0 = bx * 64;

#pragma unroll
  for (int i = 0; i < 8; ++i) {
    int g = tid + i * 256;
    int r = g >> 5, c = g & 31;
    int cs = c ^ (r & 31);
    *(uint4*)&As[(r * 32 + cs) * 8] = *(const uint4*)&Ab[(size_t)(m0 + r) * 256 + c * 8];
    *(uint4*)&Bs[(r * 32 + cs) * 8] = *(const uint4*)&Bb[(size_t)(n0 + r) * 256 + c * 8];
  }
  __syncthreads();

  int wave = tid >> 6, lane = tid & 63;
  int wm = (wave >> 1) * 32, wn = (wave & 1) * 32;
  int l16 = lane & 15, quad = lane >> 4;

  f32x4_t acc[2][2];
#pragma unroll
  for (int f = 0; f < 2; ++f)
#pragma unroll
    for (int g = 0; g < 2; ++g) acc[f][g] = (f32x4_t){0.f, 0.f, 0.f, 0.f};

  int arow[2] = {wm + l16, wm + 16 + l16};
  int brow[2] = {wn + l16, wn + 16 + l16};

#pragma unroll
  for (int kc = 0; kc < 8; ++kc) {
    int cl = kc * 4 + quad;
    bf16x8_t af[2], bf[2];
#pragma unroll
    for (int f = 0; f < 2; ++f) {
      af[f] = *(const bf16x8_t*)&As[(arow[f] * 32 + (cl ^ (arow[f] & 31))) * 8];
      bf[f] = *(const bf16x8_t*)&Bs[(brow[f] * 32 + (cl ^ (brow[f] & 31))) * 8];
    }
#pragma unroll
    for (int f = 0; f < 2; ++f)
#pragma unroll
      for (int g = 0; g < 2; ++g)
        acc[f][g] = __builtin_amdgcn_mfma_f32_16x16x32_bf16(af[f], bf[g], acc[f][g], 0, 0, 0);
  }
  __syncthreads();   // all LDS reads done; reuse As as C staging

  ushort* Cs = As;   // 64 x CPAD(72) ushorts = 9 KB
#pragma unroll
  for (int g = 0; g < 2; ++g) {
    int col = wn + g * 16 + l16;
    float bias = brel[n0 + col];
#pragma unroll
    for (int f = 0; f < 2; ++f) {
      int rowb = wm + f * 16 + quad * 4;
#pragma unroll
      for (int r = 0; r < 4; ++r) {
        float v = fmaxf(acc[f][g][r] + bias, 0.f);
        Cs[(rowb + r) * CPAD + col] = f2bf(v);
      }
    }
  }
  __syncthreads();
  {
    int r = tid >> 2, co = (tid & 3) * 16;
    uint4 v0 = *(uint4*)&Cs[r * CPAD + co];
    uint4 v1 = *(uint4*)&Cs[r * CPAD + co + 8];
    *(uint4*)&hw[(size_t)(m0 + r) * 512 + n0 + co] = v0;
    *(uint4*)&hw[(size_t)(m0 + r) * 512 + n0 + co + 8] = v1;
  }
}

// ---------------------------------------------------------------------------
// Kernel D+F fused: per node s (softmax of h.Wpool+b), s/s_logits stores,
// out[b,c,:] partials -> outpart. XCD-locality: blk&7 = graph.
// ---------------------------------------------------------------------------
__global__ __launch_bounds__(256) void pool_node(
    const ushort* __restrict__ hw, const float* __restrict__ Wp,
    const float* __restrict__ bp, float* __restrict__ s,
    float* __restrict__ slog, float* __restrict__ outpart,
    float* __restrict__ ssacc) {
  __shared__ float red[4][1024];   // 16 KB
  __shared__ float ssr[4][3];
  int blk = blockIdx.x;            // 512 blocks
  int b = blk & 7;                 // graph = XCD
  int chunk = blk >> 3;            // 0..63
  int obik = b * 64 + chunk;       // outpart index
  int wave = threadIdx.x >> 6, lane = threadIdx.x & 63;
  int n0 = b * NN + chunk * 64 + wave * 16;
  int f0 = lane * 8;

  float wp0[8], wp1[8];
#pragma unroll
  for (int j = 0; j < 8; ++j) {
    wp0[j] = Wp[(f0 + j) * 2];
    wp1[j] = Wp[(f0 + j) * 2 + 1];
  }
  float bp0 = bp[0], bp1 = bp[1];
  float o0[8] = {0, 0, 0, 0, 0, 0, 0, 0};
  float o1[8] = {0, 0, 0, 0, 0, 0, 0, 0};
  float sa = 0.f, sb = 0.f, sc2 = 0.f;

  for (int i = 0; i < 16; ++i) {
    int n = n0 + i;
    bf16x8_t hv = *(const bf16x8_t*)&hw[(size_t)n * HID + f0];
    const ushort* hp = (const ushort*)&hv;
    float h[8];
    float a0 = 0.f, a1 = 0.f;
#pragma unroll
    for (int j = 0; j < 8; ++j) {
      h[j] = bf2f(hp[j]);
      a0 += h[j] * wp0[j];
      a1 += h[j] * wp1[j];
    }
#pragma unroll
    for (int off = 32; off; off >>= 1) {
      a0 += __shfl_down(a0, off, 64);
      a1 += __shfl_down(a1, off, 64);
    }
    float s0 = 0.f, s1 = 0.f;
    if (lane == 0) {
      float l0 = a0 + bp0, l1 = a1 + bp1;
      slog[n * 2] = l0;
      slog[n * 2 + 1] = l1;
      float m = fmaxf(l0, l1);
      float e0 = expf(l0 - m), e1 = expf(l1 - m);
      float inv = 1.f / (e0 + e1);
      s0 = e0 * inv; s1 = e1 * inv;
      s[n * 2] = s0;
      s[n * 2 + 1] = s1;
      sa += s0 * s0; sb += s0 * s1; sc2 += s1 * s1;
    }
    s0 = __shfl(s0, 0, 64);
    s1 = __shfl(s1, 0, 64);
#pragma unroll
    for (int j = 0; j < 8; ++j) {
      o0[j] += s0 * h[j];
      o1[j] += s1 * h[j];
    }
  }

#pragma unroll
  for (int j = 0; j < 8; ++j) {
    red[wave][f0 + j] = o0[j];
    red[wave][512 + f0 + j] = o1[j];
  }
  if (lane == 0) { ssr[wave][0] = sa; ssr[wave][1] = sb; ssr[wave][2] = sc2; }
  __syncthreads();
  int t = threadIdx.x;
#pragma unroll
  for (int q = 0; q < 4; ++q) {
    int idx = t + q * 256;
    float v = red[0][idx] + red[1][idx] + red[2][idx] + red[3][idx];
    outpart[(size_t)obik * 1024 + idx] = v;
  }
  if (t < 3) {
    float v = ssr[0][t] + ssr[1][t] + ssr[2][t] + ssr[3][t];
    atomicAdd(&ssacc[b * 4 + t], v);
  }
}

// ---------------------------------------------------------------------------
// Kernel E: out_adj_raw[b,i,j] = sum_e w_e * s[src,i] * s[dst,j]
// + mincut_den[b]. XCD-locality: blk&7 = graph.
// ---------------------------------------------------------------------------
__global__ __launch_bounds__(256) void edge_pass2(
    const int* __restrict__ src, const int* __restrict__ dst,
    const float* __restrict__ ew, const float* __restrict__ s,
    float* __restrict__ oadj, float* __restrict__ mden) {
  int b = blockIdx.x & 7;
  int sub = blockIdx.x >> 3;
  int base = b * EE + sub * 1024;
  float p00 = 0, p01 = 0, p10 = 0, p11 = 0, md = 0;
  for (int i = threadIdx.x; i < 1024; i += 256) {
    int e = base + i;
    int r = src[e], c = dst[e];
    float w = ew[e];
    float s0r = s[r * 2], s1r = s[r * 2 + 1];
    float s0c = s[c * 2], s1c = s[c * 2 + 1];
    p00 += w * s0r * s0c; p01 += w * s0r * s1c;
    p10 += w * s1r * s0c; p11 += w * s1r * s1c;
    md  += w * (s0r * s0r + s1r * s1r);
  }
#pragma unroll
  for (int off = 32; off; off >>= 1) {
    p00 += __shfl_down(p00, off, 64);
    p01 += __shfl_down(p01, off, 64);
    p10 += __shfl_down(p10, off, 64);
    p11 += __shfl_down(p11, off, 64);
    md  += __shfl_down(md,  off, 64);
  }
  __shared__ float red[4][5];
  int wave = threadIdx.x >> 6, lane = threadIdx.x & 63;
  if (lane == 0) {
    red[wave][0] = p00; red[wave][1] = p01;
    red[wave][2] = p10; red[wave][3] = p11;
    red[wave][4] = md;
  }
  __syncthreads();
  if (threadIdx.x < 4) {
    float v = red[0][threadIdx.x] + red[1][threadIdx.x] +
              red[2][threadIdx.x] + red[3][threadIdx.x];
    atomicAdd(&oadj[b * 4 + threadIdx.x], v);
  } else if (threadIdx.x == 4) {
    float v = red[0][4] + red[1][4] + red[2][4] + red[3][4];
    atomicAdd(&mden[b], v);
  }
}

// ---------------------------------------------------------------------------
// Kernel H: fused tail stage 1. 64 blocks = (graph b = blk>>3) x (fc = blk&7).
// Per block: scalars from oadj/ssacc/mden (fc==0 writes losses + out_adj),
// redundant uv-reduction of outpart (256KB), h2 chunk = relu(u@Wa+v@Wb+bc),
// partial logits atomicAdd into lacc. Replaces finalize_a+conv3+lin1.
// ---------------------------------------------------------------------------
__global__ __launch_bounds__(256) void h2logits(
    const float* __restrict__ outpart, const float* __restrict__ oadj,
    const float* __restrict__ ssacc, const float* __restrict__ mden,
    const float* __restrict__ Wa, const float* __restrict__ Wb,
    const float* __restrict__ bcv, const float* __restrict__ Wlin2,
    float* __restrict__ lacc, float* __restrict__ dout) {
  __shared__ float oarr[1024];
  __shared__ float red[4][64];
  __shared__ float sc[2];
  int b = blockIdx.x >> 3, fc = blockIdx.x & 7;
  int t = threadIdx.x;
  if (t == 0) {
    float r00 = oadj[b * 4 + 0], r01 = oadj[b * 4 + 1];
    float r10 = oadj[b * 4 + 2], r11 = oadj[b * 4 + 3];
    float d20 = sqrtf(r01) + 1e-15f;
    float d21 = sqrtf(r10) + 1e-15f;
    float oa01 = r01 / (d20 * d21);
    float oa10 = r10 / (d21 * d20);
    sc[0] = oa01; sc[1] = oa10;
    if (fc == 0) {
      atomicAdd(&dout[80], -((r00 + r11) / mden[b]) / (float)BB);
      float a = ssacc[b * 4 + 0], bb = ssacc[b * 4 + 1], c = ssacc[b * 4 + 2];
      float nrm = sqrtf(a * a + 2.f * bb * bb + c * c);
      float q = 0.70710678118654752f;
      float da = a / nrm - q, db = bb / nrm, dc = c / nrm - q;
      atomicAdd(&dout[81], sqrtf(da * da + 2.f * db * db + dc * dc) / (float)BB);
      dout[65618 + b * 4 + 0] = 0.f;
      dout[65618 + b * 4 + 1] = oa01;
      dout[65618 + b * 4 + 2] = oa10;
      dout[65618 + b * 4 + 3] = 0.f;
    }
  }
  // uv partial sums: oarr[k]=o0[k], oarr[512+k]=o1[k]
#pragma unroll
  for (int q = 0; q < 4; ++q) {
    int idx = t + q * 256;
    float sacc = 0.f;
    for (int i = 0; i < 64; ++i)
      sacc += outpart[(size_t)(b * 64 + i) * 1024 + idx];
    oarr[idx] = sacc;
  }
  __syncthreads();
  float oa01 = sc[0], oa10 = sc[1];
  int f = fc * 64 + (t & 63);
  int ks = t >> 6;
  float acc = 0.f;
  for (int kq = 0; kq < 128; ++kq) {
    int k = ks * 128 + kq;
    float o0 = oarr[k], o1 = oarr[512 + k];
    float u = oa10 * o1 + oa01 * o0;
    float v = o0 + o1;
    acc += u * Wa[k * 512 + f] + v * Wb[k * 512 + f];
  }
  red[ks][t & 63] = acc;
  __syncthreads();
  if (t < 64) {
    int ff = fc * 64 + t;
    float h2 = red[0][t] + red[1][t] + red[2][t] + red[3][t] + bcv[ff];
    h2 = fmaxf(h2, 0.f);
#pragma unroll
    for (int o = 0; o < OUTC; ++o) {
      float lp = h2 * Wlin2[ff * OUTC + o];
#pragma unroll
      for (int off = 32; off; off >>= 1) lp += __shfl_down(lp, off, 64);
      if (t == 0) atomicAdd(&lacc[b * 16 + o], lp);
    }
  }
}

// ---------------------------------------------------------------------------
// Kernel I: final log_softmax from accumulated logits.
// ---------------------------------------------------------------------------
__global__ __launch_bounds__(64) void headfinal(
    const float* __restrict__ lacc, const float* __restrict__ blin2,
    float* __restrict__ dout) {
  __shared__ float lg[16];
  __shared__ float lse;
  int b = blockIdx.x, t = threadIdx.x;
  if (t < OUTC) lg[t] = lacc[b * 16 + t] + blin2[t];
  __syncthreads();
  if (t == 0) {
    float m = lg[0];
    for (int o = 1; o < OUTC; ++o) m = fmaxf(m, lg[o]);
    float se = 0.f;
    for (int o = 0; o < OUTC; ++o) se += expf(lg[o] - m);
    lse = m + logf(se);
  }
  __syncthreads();
  if (t < OUTC) dout[b * OUTC + t] = lg[t] - lse;
}

// ---------------------------------------------------------------------------
// Launcher
// ---------------------------------------------------------------------------
extern "C" void kernel_launch(void* const* d_in, const int* in_sizes, int n_in,
                              void* d_out, int out_size, void* d_ws, size_t ws_size,
                              hipStream_t stream) {
  const float* x      = (const float*)d_in[0];
  const int*   ei     = (const int*)d_in[1];
  const float* ew     = (const float*)d_in[3];
  const float* Wrel1  = (const float*)d_in[4];
  const float* brel1  = (const float*)d_in[5];
  const float* Wroot1 = (const float*)d_in[6];
  const float* Wpool  = (const float*)d_in[7];
  const float* bpool  = (const float*)d_in[8];
  const float* Wrel3  = (const float*)d_in[9];
  const float* brel3  = (const float*)d_in[10];
  const float* Wroot3 = (const float*)d_in[11];
  const float* Wlin1  = (const float*)d_in[12];
  const float* blin1  = (const float*)d_in[13];
  const float* Wlin2  = (const float*)d_in[14];
  const float* blin2  = (const float*)d_in[15];
  float* out = (float*)d_out;
  float* ws  = (float*)d_ws;

  // workspace layout (float units); zero region [40960, 73928):
  //   oadj, ssacc, mden, deg, lacc
  float* oadj  = ws + 40960;                // [40960, 40992)
  float* ssacc = oadj + 32;                 // [40992, 41024)
  float* mden  = ssacc + 32;                // [41024, 41032)
  int*   deg   = (int*)(mden + 8);          // [41032, 73800)
  float* lacc  = ws + 73800;                // [73800, 73928)  zero-region end
  ushort* Ab   = (ushort*)(ws + 106568);    // 32768x256 bf16  [106568, 4300872)
  ushort* Bb   = (ushort*)(ws + 4300872);   // 512x256 bf16    [4300872, 4366408)
  ushort* hbf  = (ushort*)(ws + 4366408);   // 32768x512 bf16  [4366408, 12755016)
  float* outpart = ws + 12763208;           // 512*1024        [12763208, 13287496)
  // tail linear-collapse weights (ws is ~256MiB; placed clear of everything):
  float* Wa  = ws + 16000000;               // 512x512         [16000000, 16262144)
  float* Wb  = ws + 16262144;               // 512x512         [16262144, 16524288)
  float* bcv = ws + 16524288;               // 512             [16524288, 16524800)
  // aliases (lifetimes by stream order):
  int2*  ell   = (int2*)(ws + 4366408);     // 16.8MB inside hbf region, dead pre-gemm
  float* s     = ws + 106568;               // overlays Ab; Ab dead after gemm

  const int* src = ei;
  const int* dst = ei + BE;

  hipMemsetAsync(ws + 40960, 0, (size_t)32968 * sizeof(float), stream);
  hipMemsetAsync(out + 80, 0, 2 * sizeof(float), stream);

  front      <<<7176, 256, 0, stream>>>(src, dst, ew, x, Wrel1, Wroot1,
                                        Wrel3, Wroot3, brel3, Wlin1, blin1,
                                        deg, ell, Ab, Bb, Wa, Wb, bcv);
  gather_ell <<<BN / 4, 256, 0, stream>>>(deg, ell, Ab);
  gemm_mfma  <<<4096, 256, 0, stream>>>(Ab, Bb, brel1, hbf);
  pool_node  <<<512, 256, 0, stream>>>(hbf, Wpool, bpool, s, out + 82, outpart, ssacc);
  edge_pass2 <<<BB * 64, 256, 0, stream>>>(src, dst, ew, s, oadj, mden);
  h2logits   <<<64, 256, 0, stream>>>(outpart, oadj, ssacc, mden,
                                      Wa, Wb, bcv, Wlin2, lacc, out);
  headfinal  <<<BB, 64, 0, stream>>>(lacc, blin2, out);
}